// Round 8
// baseline (418.968 us; speedup 1.0000x reference)
//
#include <hip/hip_runtime.h>
#include <hip/hip_bf16.h>

// ---------------------------------------------------------------------------
// Transformer block on MI355X (gfx950), bf16 MFMA path.
// Shapes: B=2, T=2048, D=1024, H=16, d=64, FF=4096.  M = B*T = 4096.
// ---------------------------------------------------------------------------

typedef __attribute__((ext_vector_type(8))) short short8;   // 8 x bf16 (4 VGPRs)
typedef __attribute__((ext_vector_type(4))) float f32x4;
typedef __attribute__((ext_vector_type(4))) unsigned short u16x4;
typedef __attribute__((ext_vector_type(8))) unsigned short u16x8;

#define MROWS 4096
#define DMODEL 1024
#define DFF 4096
#define NH 16
#define HD 64
#define SEQ 2048

static __device__ __forceinline__ unsigned short f2bf(float f) {
    union { __hip_bfloat16 b; unsigned short u; } cv;
    cv.b = __float2bfloat16(f);
    return cv.u;
}

static __device__ __forceinline__ void gload_lds16(const void* g, void* l) {
    __builtin_amdgcn_global_load_lds(
        (const __attribute__((address_space(1))) unsigned int*)g,
        (__attribute__((address_space(3))) unsigned int*)l, 16, 0, 0);
}

// Bijective XCD-chunked remap (m204): blocks resident on one XCD process a
// contiguous chunk of the linearized grid (L2 locality).
static __device__ __forceinline__ int xcd_swizzle(int id, int nwg) {
    const int nx = 8;
    const int q = nwg / nx, r = nwg % nx;
    const int xcd = id % nx, loc = id / nx;
    return (xcd < r ? xcd * (q + 1) : r * (q + 1) + (xcd - r) * q) + loc;
}

// ---------------------------------------------------------------------------
// Weight cast+transpose: W [K][N] f32 -> Wt [N][K] bf16 (so GEMM reads contig K)
// ---------------------------------------------------------------------------
__global__ void cast_transpose(const float* __restrict__ W,
                               unsigned short* __restrict__ Wt, int K, int N) {
    __shared__ float tile[32][33];
    const int tx = threadIdx.x & 31;
    const int ty = threadIdx.x >> 5;          // 0..7
    const int n0 = blockIdx.x * 32, k0 = blockIdx.y * 32;
#pragma unroll
    for (int i = 0; i < 4; ++i) {
        int kk = ty + i * 8;
        tile[kk][tx] = W[(long)(k0 + kk) * N + n0 + tx];
    }
    __syncthreads();
#pragma unroll
    for (int i = 0; i < 4; ++i) {
        int nn = ty + i * 8;
        Wt[(long)(n0 + nn) * K + k0 + tx] = f2bf(tile[tx][nn]);
    }
}

// ---------------------------------------------------------------------------
// RoPE tables: cos/sin [T][32]; j<16 real freqs 1024^(-j/15), j>=16 identity.
// ---------------------------------------------------------------------------
__global__ void rope_table(float* __restrict__ cosT, float* __restrict__ sinT) {
    const int t = blockIdx.x, j = threadIdx.x;   // block=32
    float th = (j < 16) ? (float)t * exp2f(-(10.0f / 15.0f) * (float)j) : 0.0f;
    cosT[t * 32 + j] = cosf(th);
    sinT[t * 32 + j] = sinf(th);
}

// ---------------------------------------------------------------------------
// RMSNorm over D=1024, f32 in -> bf16 out.  One block (256 thr) per row.
// ---------------------------------------------------------------------------
__global__ void rmsnorm_cast(const float* __restrict__ xin,
                             unsigned short* __restrict__ hout) {
    const int row = blockIdx.x;
    const float4 v = ((const float4*)(xin + (long)row * DMODEL))[threadIdx.x];
    float ss = v.x * v.x + v.y * v.y + v.z * v.z + v.w * v.w;
#pragma unroll
    for (int m = 32; m >= 1; m >>= 1) ss += __shfl_xor(ss, m);
    __shared__ float part[4];
    if ((threadIdx.x & 63) == 0) part[threadIdx.x >> 6] = ss;
    __syncthreads();
    const float tot = part[0] + part[1] + part[2] + part[3];
    const float sc = rsqrtf(tot * (1.0f / (float)DMODEL) + 1e-6f);
    ushort4 o;
    o.x = f2bf(v.x * sc); o.y = f2bf(v.y * sc);
    o.z = f2bf(v.z * sc); o.w = f2bf(v.w * sc);
    ((ushort4*)hout)[(long)row * (DMODEL / 4) + threadIdx.x] = o;
}

// ---------------------------------------------------------------------------
// gemm256: 256x256 tile, BK=32 sub-tiles, 8 waves (2Mx4N), 512 threads.
// 4-slot LDS ring (128 KB), prefetch depth 3, counted vmcnt(8) per sub-tile
// (never 0 in steady state).  Each wave issues exactly 4 global_load_lds per
// sub-tile, so vmcnt(8) = "the two newer tiles may stay in flight".
// LDS layout per matrix sub-tile: [128 lines][64 bf16]; line L holds row L
// (k 0..31, chunks 0-3) and row L+128 (chunks 4-7); 16B chunk XOR-swizzled by
// (L&7) -- inverse swizzle applied to the GLOBAL source (rule 21).
// EPI 0: outF = acc+bias (f32)  [QKV];  EPI 2: outB = bf16(gelu(acc+bias)) [MLP1]
// ---------------------------------------------------------------------------
template <int EPI>
__launch_bounds__(512, 2)
__global__ void gemm256(const short* __restrict__ A, const short* __restrict__ Bt,
                        const float* __restrict__ bias,
                        float* __restrict__ outF, unsigned short* __restrict__ outB,
                        int N, int K) {
    __shared__ __align__(16) short As[4][128 * 64];
    __shared__ __align__(16) short Bs[4][128 * 64];
    const int tid = threadIdx.x;
    const int lane = tid & 63, w = tid >> 6;
    const int wr = w >> 2, wc = w & 3;            // 2 x 4 wave grid
    const int l16 = lane & 15, lhi = lane >> 4;

    const int nwg = gridDim.x * gridDim.y;
    int id = xcd_swizzle(blockIdx.y * gridDim.x + blockIdx.x, nwg);
    const int bx = id % gridDim.x, by = id / gridDim.x;
    const long rowA0 = (long)by * 256;
    const long rowB0 = (long)bx * 256;

    const f32x4 fz = {0.f, 0.f, 0.f, 0.f};
    f32x4 acc[8][4];
#pragma unroll
    for (int m = 0; m < 8; ++m)
#pragma unroll
        for (int n = 0; n < 4; ++n) acc[m][n] = fz;

    auto stage = [&](int kt, int b) {
        const int k0 = kt << 5;
#pragma unroll
        for (int pass = 0; pass < 2; ++pass) {
            const int c = pass * 512 + tid;       // 0..1023 16B-chunks
            const int line = c >> 3, pch = c & 7;
            const int lch = pch ^ (line & 7);     // logical chunk
            const int row = ((lch >> 2) << 7) + line;
            const int kc = (lch & 3) << 3;        // k offset in elements
            gload_lds16(A + (rowA0 + row) * K + k0 + kc, (char*)&As[b][0] + c * 16);
            gload_lds16(Bt + (rowB0 + row) * K + k0 + kc, (char*)&Bs[b][0] + c * 16);
        }
    };
    auto compute = [&](int b) {
        const short* Ab = &As[b][0];
        const short* Bb = &Bs[b][0];
        short8 af[8], bf[4];
#pragma unroll
        for (int m = 0; m < 8; ++m) {
            const int line = m * 16 + l16;        // A row = wr*128 + line
            const int pch = ((wr << 2) + lhi) ^ (line & 7);
            af[m] = *(const short8*)(Ab + line * 64 + pch * 8);
        }
#pragma unroll
        for (int n = 0; n < 4; ++n) {
            const int row = wc * 64 + n * 16 + l16;
            const int line = row & 127;
            const int pch = (((row >> 7) << 2) + lhi) ^ (line & 7);
            bf[n] = *(const short8*)(Bb + line * 64 + pch * 8);
        }
#pragma unroll
        for (int m = 0; m < 8; ++m)
#pragma unroll
            for (int n = 0; n < 4; ++n)
                acc[m][n] = __builtin_amdgcn_mfma_f32_16x16x32_bf16(
                    af[m], bf[n], acc[m][n], 0, 0, 0);
    };

    const int ktiles = K >> 5;                    // 32 for K=1024
    stage(0, 0);
    stage(1, 1);
    stage(2, 2);
    for (int t = 0; t < ktiles; ++t) {
        const int rem = ktiles - 1 - t;
        if (rem >= 2)      asm volatile("s_waitcnt vmcnt(8)" ::: "memory");
        else if (rem == 1) asm volatile("s_waitcnt vmcnt(4)" ::: "memory");
        else               asm volatile("s_waitcnt vmcnt(0)" ::: "memory");
        __builtin_amdgcn_s_barrier();
        __builtin_amdgcn_sched_barrier(0);
        if (t + 3 < ktiles) stage(t + 3, (t + 3) & 3);   // after barrier: slot free
        compute(t & 3);
    }

#pragma unroll
    for (int m = 0; m < 8; ++m) {
        const long r0 = rowA0 + wr * 128 + m * 16 + lhi * 4;
#pragma unroll
        for (int n = 0; n < 4; ++n) {
            const long cc = rowB0 + wc * 64 + n * 16 + l16;
            const float bv = bias[cc];
#pragma unroll
            for (int j = 0; j < 4; ++j) {
                const long idx = (r0 + j) * N + cc;
                float v = acc[m][n][j] + bv;
                if (EPI == 2) {
                    float g = 0.5f * v *
                        (1.0f + tanhf(0.7978845608028654f * (v + 0.044715f * v * v * v)));
                    outB[idx] = f2bf(g);
                } else {
                    outF[idx] = v;
                }
            }
        }
    }
}

// ---------------------------------------------------------------------------
// GEMM: C[M,N] = A[M,K](bf16) @ Bt[N,K]^T(bf16) + bias
// 128 x BN tile (BN = 128 or 64), BK = 32 or 64, 4 waves (2x2).
// 2-phase double-buffer (kept for the N=1024 GEMMs: Wo, MLP2).
// EPI 1: outF = acc+bias+res (f32)
// ---------------------------------------------------------------------------
template <int EPI, int BN, int BK>
__launch_bounds__(256)
__global__ void gemm_bt(const short* __restrict__ A, const short* __restrict__ Bt,
                        const float* __restrict__ bias, const float* __restrict__ res,
                        float* __restrict__ outF, unsigned short* __restrict__ outB,
                        int N, int K) {
    constexpr int NF = BN / 32;               // n-frags per wave
    constexpr int CPR = BK / 8;               // 16B chunks per row
    __shared__ short As[2][128 * BK];
    __shared__ short Bs[2][BN * BK];
    const int tid = threadIdx.x;
    const int lane = tid & 63, w = tid >> 6;
    const int wr = w >> 1, wc = w & 1;
    const int l16 = lane & 15, lhi = lane >> 4;

    const int nwg = gridDim.x * gridDim.y;
    int id = xcd_swizzle(blockIdx.y * gridDim.x + blockIdx.x, nwg);
    const int bx = id % gridDim.x, by = id / gridDim.x;
    const long rowA0 = (long)by * 128;
    const long rowB0 = (long)bx * BN;

    const f32x4 fz = {0.f, 0.f, 0.f, 0.f};
    f32x4 acc[4][NF];
#pragma unroll
    for (int m = 0; m < 4; ++m)
#pragma unroll
        for (int n = 0; n < NF; ++n) acc[m][n] = fz;

    auto stage = [&](int kt, int b) {
        const int k0 = kt * BK;
#pragma unroll
        for (int it = 0; it < BK / 16; ++it) {
            const int c = it * 256 + tid;
            const int r = c / CPR, col = (c % CPR) * 8;
            gload_lds16(A + (rowA0 + r) * K + k0 + col, (char*)As[b] + c * 16);
        }
#pragma unroll
        for (int it = 0; it < (BN * BK) / 2048; ++it) {
            const int c = it * 256 + tid;
            const int r = c / CPR, col = (c % CPR) * 8;
            gload_lds16(Bt + (rowB0 + r) * K + k0 + col, (char*)Bs[b] + c * 16);
        }
    };
    auto compute = [&](int b) {
#pragma unroll
        for (int kk = 0; kk < BK / 32; ++kk) {
            short8 af[4], bf[NF];
#pragma unroll
            for (int m = 0; m < 4; ++m)
                af[m] = *(const short8*)(&As[b][0] + (wr * 64 + m * 16 + l16) * BK + kk * 32 + lhi * 8);
#pragma unroll
            for (int n = 0; n < NF; ++n)
                bf[n] = *(const short8*)(&Bs[b][0] + (wc * (BN / 2) + n * 16 + l16) * BK + kk * 32 + lhi * 8);
#pragma unroll
            for (int m = 0; m < 4; ++m)
#pragma unroll
                for (int n = 0; n < NF; ++n)
                    acc[m][n] = __builtin_amdgcn_mfma_f32_16x16x32_bf16(
                        af[m], bf[n], acc[m][n], 0, 0, 0);
        }
    };

    const int ktiles = K / BK;
    stage(0, 0);
    __syncthreads();
    int cur = 0;
    for (int kt = 0; kt < ktiles; ++kt) {
        if (kt + 1 < ktiles) stage(kt + 1, cur ^ 1);
        compute(cur);
        __syncthreads();
        cur ^= 1;
    }

#pragma unroll
    for (int m = 0; m < 4; ++m) {
        const long r0 = rowA0 + wr * 64 + m * 16 + lhi * 4;
#pragma unroll
        for (int n = 0; n < NF; ++n) {
            const long cc = rowB0 + wc * (BN / 2) + n * 16 + l16;
            const float bv = bias[cc];
#pragma unroll
            for (int j = 0; j < 4; ++j) {
                const long idx = (r0 + j) * N + cc;
                float v = acc[m][n][j] + bv;
                if (EPI == 1) v += res[idx];
                if (EPI == 2) {
                    float g = 0.5f * v *
                        (1.0f + tanhf(0.7978845608028654f * (v + 0.044715f * v * v * v)));
                    outB[idx] = f2bf(g);
                } else {
                    outF[idx] = v;
                }
            }
        }
    }
}

// ---------------------------------------------------------------------------
// QKV post: per-(row,head) rmsnorm(d=64) + RoPE; write Q,K bf16 [BH][T][64].
// One wave per (row,head); 1/sqrt(HD)=1/8 folded into Q.  (V handled by
// transpose_v.)
// ---------------------------------------------------------------------------
__global__ void qkv_post(const float* __restrict__ qkv, const float* __restrict__ cosT,
                         const float* __restrict__ sinT, unsigned short* __restrict__ Qo,
                         unsigned short* __restrict__ Ko) {
    const int lane = threadIdx.x & 63;
    const int g = blockIdx.x * 4 + (threadIdx.x >> 6);
    const int row = g >> 4, h = g & 15;
    const int b = row >> 11, t = row & 2047;
    const float* base = qkv + (long)row * 3072 + h * 64;
    float q = base[lane];
    float k = base[1024 + lane];
    float sq = q * q, sk = k * k;
#pragma unroll
    for (int m = 32; m >= 1; m >>= 1) {
        sq += __shfl_xor(sq, m);
        sk += __shfl_xor(sk, m);
    }
    q *= rsqrtf(sq * (1.0f / 64.0f) + 1e-6f);
    k *= rsqrtf(sk * (1.0f / 64.0f) + 1e-6f);
    const int j = lane & 31;
    const float c = cosT[t * 32 + j], s = sinT[t * 32 + j];
    const float q2 = __shfl_xor(q, 32), k2 = __shfl_xor(k, 32);
    const float sgn = (lane < 32) ? 1.0f : -1.0f;   // y1 = x1*c + x2*s ; y2 = -x1*s + x2*c
    const float qr = q * c + sgn * q2 * s;
    const float kr = k * c + sgn * k2 * s;
    const long o = ((long)(b * 16 + h) * SEQ + t) * 64 + lane;
    Qo[o] = f2bf(qr * 0.125f);
    Ko[o] = f2bf(kr);
}

// ---------------------------------------------------------------------------
// V transpose: qkv f32 [M][3072] (V at col 2048+h*64+d) -> Vt bf16 [BH][64 d][T].
// Block per (bh, 64-row t-tile); LDS 64x65 f32 tile.
// ---------------------------------------------------------------------------
__global__ void transpose_v(const float* __restrict__ qkv,
                            unsigned short* __restrict__ Vt) {
    __shared__ float tile[64][65];
    const int tid = threadIdx.x;
    const int bh = blockIdx.x, tt = blockIdx.y;
    const int b = bh >> 4, h = bh & 15;
    const int tr = tid >> 2, c0 = (tid & 3) * 16;
    const float* src = qkv + ((long)(b * SEQ + tt * 64 + tr)) * 3072 + 2048 + h * 64 + c0;
#pragma unroll
    for (int i = 0; i < 4; ++i) {
        float4 v = ((const float4*)src)[i];
        tile[tr][c0 + i * 4 + 0] = v.x;
        tile[tr][c0 + i * 4 + 1] = v.y;
        tile[tr][c0 + i * 4 + 2] = v.z;
        tile[tr][c0 + i * 4 + 3] = v.w;
    }
    __syncthreads();
    const int d = tid >> 2, t0 = (tid & 3) * 16;
    unsigned short* dst = Vt + ((long)bh * 64 + d) * SEQ + tt * 64 + t0;
#pragma unroll
    for (int half = 0; half < 2; ++half) {
        u16x8 o;
#pragma unroll
        for (int e = 0; e < 8; ++e) o[e] = f2bf(tile[t0 + half * 8 + e][d]);
        *(u16x8*)(dst + half * 8) = o;
    }
}

// ---------------------------------------------------------------------------
// Causal flash attention. Block = 4 waves; Q-tile = 64 rows (16/wave); KV tile 64.
// SWAPPED QK^T: s = mfma(K, Q) so each 4-lane group owns a full q-row
// (q = lane&15, kv = frag index) -> in-lane softmax reduce + 2 shfl.
// P written [q][kv] with 4 x ds_write_b64, read back as PV A-frags (b128).
// K/V tiles double-buffered (stage(kt+1) before compute(kt)).
// Causal tiles paired: block i does qt=31-i then qt=i -> 33 steps/block flat.
// T13 defer-max: skip O-rescale when __all(pm <= m+8).
// ---------------------------------------------------------------------------
__launch_bounds__(256)
__global__ void attn_fwd(const short* __restrict__ Qg, const short* __restrict__ Kg,
                         const short* __restrict__ Vtg, unsigned short* __restrict__ Og) {
    __shared__ short Ks[2][64 * 64];          // [kv][d], chunk-XOR-swizzled
    __shared__ short Vs[2][64 * 64];          // [d][kv], chunk-XOR-swizzled
    __shared__ char Ps[4][2048];              // per-wave P [16 q][64 kv], swizzled
    const int tid = threadIdx.x, lane = tid & 63, w = tid >> 6;
    const int l16 = lane & 15, lhi = lane >> 4;
    const int id = xcd_swizzle(blockIdx.y * gridDim.x + blockIdx.x, 512);
    const int bh = id >> 4;
    const int ip = id & 15;
    const int bb = bh >> 4, hh = bh & 15;
    const long base_q = (long)bh * (SEQ * 64);
    char* Pw = &Ps[w][0];
    const int swz = (l16 & 7) << 4;
    const f32x4 fz = {0.f, 0.f, 0.f, 0.f};

#pragma unroll 1
    for (int rep = 0; rep < 2; ++rep) {
        const int qt = rep ? ip : 31 - ip;
        short8 aq0, aq1;
        {
            const short* Qp = Qg + base_q + (long)(qt * 64 + w * 16) * 64;
            aq0 = *(const short8*)(Qp + l16 * 64 + lhi * 8);
            aq1 = *(const short8*)(Qp + l16 * 64 + 32 + lhi * 8);
        }
        float mrow = -1e30f, lrow = 0.f;
        f32x4 oacc[4];
#pragma unroll
        for (int n = 0; n < 4; ++n) oacc[n] = fz;

        auto stage = [&](int kt, int b) {
            const short* Kp = Kg + base_q + (long)kt * 64 * 64;
            const short* Vp = Vtg + base_q + (long)kt * 64;
#pragma unroll
            for (int it = 0; it < 2; ++it) {
                const int c = it * 256 + tid;
                const int r = c >> 3;
                const int col = ((c & 7) ^ (r & 7)) << 3;
                gload_lds16(Kp + r * 64 + col, (char*)&Ks[b][0] + c * 16);
                gload_lds16(Vp + (long)r * SEQ + col, (char*)&Vs[b][0] + c * 16);
            }
        };

        stage(0, 0);
        __syncthreads();
        int cur = 0;
        for (int kt = 0; kt <= qt; ++kt) {
            if (kt < qt) stage(kt + 1, cur ^ 1);
            const short* KsC = &Ks[cur][0];
            const short* VsC = &Vs[cur][0];

            // S^T = K Q^T per wave: frag n covers kv = n*16..n*16+15 for the
            // wave's 16 q.  Lane holds s[n][j] = S[kv=n*16+lhi*4+j][q=l16].
            f32x4 s[4];
            __builtin_amdgcn_s_setprio(1);
#pragma unroll
            for (int n = 0; n < 4; ++n) {
                const int kr = n * 16 + l16;
                short8 bk0 = *(const short8*)(KsC + kr * 64 + ((lhi ^ (kr & 7)) << 3));
                short8 bk1 = *(const short8*)(KsC + kr * 64 + (((lhi + 4) ^ (kr & 7)) << 3));
                f32x4 z = fz;
                z = __builtin_amdgcn_mfma_f32_16x16x32_bf16(bk0, aq0, z, 0, 0, 0);
                s[n] = __builtin_amdgcn_mfma_f32_16x16x32_bf16(bk1, aq1, z, 0, 0, 0);
            }
            __builtin_amdgcn_s_setprio(0);
            if (kt == qt) {   // diagonal tile causal mask: kv_local > q_local
#pragma unroll
                for (int n = 0; n < 4; ++n)
#pragma unroll
                    for (int j = 0; j < 4; ++j)
                        if (n * 16 + lhi * 4 + j > w * 16 + l16) s[n][j] = -1e30f;
            }

            // online softmax: lane owns 16 of the 64 kv for q=l16; full-row
            // reduce = in-lane + shfl_xor(16,32).
            float pm = s[0][0];
#pragma unroll
            for (int n = 0; n < 4; ++n)
#pragma unroll
                for (int j = 0; j < 4; ++j) pm = fmaxf(pm, s[n][j]);
            pm = fmaxf(pm, __shfl_xor(pm, 16));
            pm = fmaxf(pm, __shfl_xor(pm, 32));
            if (!__all(pm <= mrow + 8.f)) {       // T13 defer-max
                const float newm = fmaxf(mrow, pm);
                const float sc = __expf(mrow - newm);
                mrow = newm;
                lrow *= sc;
#pragma unroll
                for (int j = 0; j < 4; ++j) {
                    const float scj = __shfl(sc, lhi * 4 + j);
#pragma unroll
                    for (int n = 0; n < 4; ++n) oacc[n][j] *= scj;
                }
            }
            float ps = 0.f;
#pragma unroll
            for (int n = 0; n < 4; ++n)
#pragma unroll
                for (int j = 0; j < 4; ++j) {
                    const float p = __expf(s[n][j] - mrow);
                    s[n][j] = p;
                    ps += p;
                }
            ps += __shfl_xor(ps, 16);
            ps += __shfl_xor(ps, 32);
            lrow += ps;

            // P[q=l16][kv=n*16+lhi*4 ..+3]: one packed b64 write per n-frag
#pragma unroll
            for (int n = 0; n < 4; ++n) {
                u16x4 pk;
                pk[0] = f2bf(s[n][0]);
                pk[1] = f2bf(s[n][1]);
                pk[2] = f2bf(s[n][2]);
                pk[3] = f2bf(s[n][3]);
                *(u16x4*)(Pw + ((l16 * 128 + n * 32 + lhi * 8) ^ swz)) = pk;
            }

            // O += P @ V : A-frag b128 from P[q][kv], B-frag from Vs
            __builtin_amdgcn_s_setprio(1);
#pragma unroll
            for (int ks = 0; ks < 2; ++ks) {
                short8 pa = *(const short8*)(Pw + ((l16 * 128 + ks * 64 + lhi * 16) ^ swz));
#pragma unroll
                for (int n = 0; n < 4; ++n) {
                    const int dr = n * 16 + l16;
                    short8 vb = *(const short8*)(VsC + dr * 64 + ((((ks << 2) + lhi) ^ (dr & 7)) << 3));
                    oacc[n] = __builtin_amdgcn_mfma_f32_16x16x32_bf16(pa, vb, oacc[n], 0, 0, 0);
                }
            }
            __builtin_amdgcn_s_setprio(0);
            __syncthreads();
            cur ^= 1;
        }

        // epilogue: O row q=lhi*4+j needs lrow held by lane q (l16=q)
#pragma unroll
        for (int j = 0; j < 4; ++j) {
            const float lr = __shfl(lrow, lhi * 4 + j);
            const int qrow = qt * 64 + w * 16 + lhi * 4 + j;
            const long orow = (long)bb * SEQ + qrow;
#pragma unroll
            for (int n = 0; n < 4; ++n)
                Og[orow * DMODEL + hh * 64 + n * 16 + l16] = f2bf(oacc[n][j] / lr);
        }
    }
}

// ---------------------------------------------------------------------------
extern "C" void kernel_launch(void* const* d_in, const int* in_sizes, int n_in,
                              void* d_out, int out_size, void* d_ws, size_t ws_size,
                              hipStream_t stream) {
    const float* x    = (const float*)d_in[0];
    // d_in[1] = block_mask (causal tril) — implicit in the attention kernel
    const float* Wqkv = (const float*)d_in[2];
    const float* bqkv = (const float*)d_in[3];
    const float* Wo   = (const float*)d_in[4];
    const float* bo   = (const float*)d_in[5];
    const float* W1   = (const float*)d_in[6];
    const float* b1   = (const float*)d_in[7];
    const float* W2   = (const float*)d_in[8];
    const float* b2   = (const float*)d_in[9];
    float* out = (float*)d_out;

    char* ws = (char*)d_ws;
    auto alloc = [&](size_t b) {
        char* p = ws;
        ws += (b + 255) & ~(size_t)255;
        return p;
    };
    short* WqkvT = (short*)alloc(3072ull * 1024 * 2);   // [3072][1024]
    short* WoT   = (short*)alloc(1024ull * 1024 * 2);   // [1024][1024]
    short* W1T   = (short*)alloc(4096ull * 1024 * 2);   // [4096][1024]
    short* W2T   = (short*)alloc(1024ull * 4096 * 2);   // [1024][4096]
    float* cosT  = (float*)alloc(2048ull * 32 * 4);
    float* sinT  = (float*)alloc(2048ull * 32 * 4);
    short* hbuf  = (short*)alloc((size_t)MROWS * DMODEL * 2);   // h1 / h2 (shared)
    short* Qb    = (short*)alloc(32ull * SEQ * 64 * 2);
    short* Kb    = (short*)alloc(32ull * SEQ * 64 * 2);
    short* Vtb   = (short*)alloc(32ull * 64 * SEQ * 2);         // V^T per head
    short* Ob    = (short*)alloc((size_t)MROWS * DMODEL * 2);
    float* x1    = (float*)alloc((size_t)MROWS * DMODEL * 4);
    char*  big   = alloc((size_t)MROWS * 3072 * 4);     // qkv f32, later act bf16
    float* qkv   = (float*)big;
    unsigned short* act = (unsigned short*)big;

    // 1. weights -> bf16 transposed
    cast_transpose<<<dim3(96, 32), 256, 0, stream>>>(Wqkv, (unsigned short*)WqkvT, 1024, 3072);
    cast_transpose<<<dim3(32, 32), 256, 0, stream>>>(Wo, (unsigned short*)WoT, 1024, 1024);
    cast_transpose<<<dim3(128, 32), 256, 0, stream>>>(W1, (unsigned short*)W1T, 1024, 4096);
    cast_transpose<<<dim3(32, 128), 256, 0, stream>>>(W2, (unsigned short*)W2T, 4096, 1024);
    // 2. RoPE tables
    rope_table<<<2048, 32, 0, stream>>>(cosT, sinT);
    // 3. h1 = rmsnorm(x)
    rmsnorm_cast<<<MROWS, 256, 0, stream>>>(x, (unsigned short*)hbuf);
    // 4. qkv = h1 @ Wqkv + bqkv   (256^2 ring-buffer GEMM, 192 blocks)
    gemm256<0><<<dim3(12, 16), 512, 0, stream>>>(hbuf, WqkvT, bqkv, qkv, nullptr, 3072, 1024);
    // 5a. per-head rmsnorm + rope -> Q,K bf16
    qkv_post<<<16384, 256, 0, stream>>>(qkv, cosT, sinT,
                                        (unsigned short*)Qb, (unsigned short*)Kb);
    // 5b. V -> bf16 transposed per head
    transpose_v<<<dim3(32, 32), 256, 0, stream>>>(qkv, (unsigned short*)Vtb);
    // 6. causal attention -> O  (512 balanced blocks: qt pairs)
    attn_fwd<<<dim3(16, 32), 256, 0, stream>>>(Qb, Kb, Vtb, (unsigned short*)Ob);
    // 7. x1 = O @ Wo + bo + x  (BK=64: 16 K-steps)
    gemm_bt<1, 64, 64><<<dim3(16, 32), 256, 0, stream>>>(Ob, WoT, bo, x, x1, nullptr, 1024, 1024);
    // 8. h2 = rmsnorm(x1)
    rmsnorm_cast<<<MROWS, 256, 0, stream>>>(x1, (unsigned short*)hbuf);
    // 9. act = gelu(h2 @ W1 + b1)   (256^2 ring-buffer GEMM, 256 blocks)
    gemm256<2><<<dim3(16, 16), 512, 0, stream>>>(hbuf, W1T, b1, nullptr, act, 4096, 1024);
    // 10. out = act @ W2 + b2 + x1  (BK=64: 64 K-steps)
    gemm_bt<1, 64, 64><<<dim3(16, 32), 256, 0, stream>>>((const short*)act, W2T, b2, x1, out, nullptr, 1024, 4096);
}

// Round 9
// 392.864 us; speedup vs baseline: 1.0664x; 1.0664x over previous
//
#include <hip/hip_runtime.h>
#include <hip/hip_bf16.h>

// ---------------------------------------------------------------------------
// Transformer block on MI355X (gfx950), bf16 MFMA path.
// Shapes: B=2, T=2048, D=1024, H=16, d=64, FF=4096.  M = B*T = 4096.
// ---------------------------------------------------------------------------

typedef __attribute__((ext_vector_type(8))) short short8;   // 8 x bf16 (4 VGPRs)
typedef __attribute__((ext_vector_type(4))) float f32x4;
typedef __attribute__((ext_vector_type(4))) unsigned short u16x4;
typedef __attribute__((ext_vector_type(8))) unsigned short u16x8;

#define MROWS 4096
#define DMODEL 1024
#define DFF 4096
#define NH 16
#define HD 64
#define SEQ 2048

static __device__ __forceinline__ unsigned short f2bf(float f) {
    union { __hip_bfloat16 b; unsigned short u; } cv;
    cv.b = __float2bfloat16(f);
    return cv.u;
}

static __device__ __forceinline__ void gload_lds16(const void* g, void* l) {
    __builtin_amdgcn_global_load_lds(
        (const __attribute__((address_space(1))) unsigned int*)g,
        (__attribute__((address_space(3))) unsigned int*)l, 16, 0, 0);
}

// Bijective XCD-chunked remap (m204): blocks resident on one XCD process a
// contiguous chunk of the linearized grid (L2 locality).
static __device__ __forceinline__ int xcd_swizzle(int id, int nwg) {
    const int nx = 8;
    const int q = nwg / nx, r = nwg % nx;
    const int xcd = id % nx, loc = id / nx;
    return (xcd < r ? xcd * (q + 1) : r * (q + 1) + (xcd - r) * q) + loc;
}

// ---------------------------------------------------------------------------
// Weight cast+transpose: W [K][N] f32 -> Wt [N][K] bf16 (so GEMM reads contig K)
// ---------------------------------------------------------------------------
__global__ void cast_transpose(const float* __restrict__ W,
                               unsigned short* __restrict__ Wt, int K, int N) {
    __shared__ float tile[32][33];
    const int tx = threadIdx.x & 31;
    const int ty = threadIdx.x >> 5;          // 0..7
    const int n0 = blockIdx.x * 32, k0 = blockIdx.y * 32;
#pragma unroll
    for (int i = 0; i < 4; ++i) {
        int kk = ty + i * 8;
        tile[kk][tx] = W[(long)(k0 + kk) * N + n0 + tx];
    }
    __syncthreads();
#pragma unroll
    for (int i = 0; i < 4; ++i) {
        int nn = ty + i * 8;
        Wt[(long)(n0 + nn) * K + k0 + tx] = f2bf(tile[tx][nn]);
    }
}

// ---------------------------------------------------------------------------
// RoPE tables: cos/sin [T][32]; j<16 real freqs 1024^(-j/15), j>=16 identity.
// ---------------------------------------------------------------------------
__global__ void rope_table(float* __restrict__ cosT, float* __restrict__ sinT) {
    const int t = blockIdx.x, j = threadIdx.x;   // block=32
    float th = (j < 16) ? (float)t * exp2f(-(10.0f / 15.0f) * (float)j) : 0.0f;
    cosT[t * 32 + j] = cosf(th);
    sinT[t * 32 + j] = sinf(th);
}

// ---------------------------------------------------------------------------
// RMSNorm over D=1024, f32 in -> bf16 out.  One block (256 thr) per row.
// ---------------------------------------------------------------------------
__global__ void rmsnorm_cast(const float* __restrict__ xin,
                             unsigned short* __restrict__ hout) {
    const int row = blockIdx.x;
    const float4 v = ((const float4*)(xin + (long)row * DMODEL))[threadIdx.x];
    float ss = v.x * v.x + v.y * v.y + v.z * v.z + v.w * v.w;
#pragma unroll
    for (int m = 32; m >= 1; m >>= 1) ss += __shfl_xor(ss, m);
    __shared__ float part[4];
    if ((threadIdx.x & 63) == 0) part[threadIdx.x >> 6] = ss;
    __syncthreads();
    const float tot = part[0] + part[1] + part[2] + part[3];
    const float sc = rsqrtf(tot * (1.0f / (float)DMODEL) + 1e-6f);
    ushort4 o;
    o.x = f2bf(v.x * sc); o.y = f2bf(v.y * sc);
    o.z = f2bf(v.z * sc); o.w = f2bf(v.w * sc);
    ((ushort4*)hout)[(long)row * (DMODEL / 4) + threadIdx.x] = o;
}

// ---------------------------------------------------------------------------
// gemm256: 256x256 tile, BK=32 sub-tiles, 8 waves (2Mx4N), 512 threads.
// 4-slot LDS ring (128 KB), prefetch depth 3, counted vmcnt(8) per sub-tile.
// EPI 0: outF = acc+bias (f32)  [QKV];  EPI 2: outB = bf16(gelu(acc+bias)) [MLP1]
// ---------------------------------------------------------------------------
template <int EPI>
__launch_bounds__(512, 2)
__global__ void gemm256(const short* __restrict__ A, const short* __restrict__ Bt,
                        const float* __restrict__ bias,
                        float* __restrict__ outF, unsigned short* __restrict__ outB,
                        int N, int K) {
    __shared__ __align__(16) short As[4][128 * 64];
    __shared__ __align__(16) short Bs[4][128 * 64];
    const int tid = threadIdx.x;
    const int lane = tid & 63, w = tid >> 6;
    const int wr = w >> 2, wc = w & 3;            // 2 x 4 wave grid
    const int l16 = lane & 15, lhi = lane >> 4;

    const int nwg = gridDim.x * gridDim.y;
    int id = xcd_swizzle(blockIdx.y * gridDim.x + blockIdx.x, nwg);
    const int bx = id % gridDim.x, by = id / gridDim.x;
    const long rowA0 = (long)by * 256;
    const long rowB0 = (long)bx * 256;

    const f32x4 fz = {0.f, 0.f, 0.f, 0.f};
    f32x4 acc[8][4];
#pragma unroll
    for (int m = 0; m < 8; ++m)
#pragma unroll
        for (int n = 0; n < 4; ++n) acc[m][n] = fz;

    auto stage = [&](int kt, int b) {
        const int k0 = kt << 5;
#pragma unroll
        for (int pass = 0; pass < 2; ++pass) {
            const int c = pass * 512 + tid;       // 0..1023 16B-chunks
            const int line = c >> 3, pch = c & 7;
            const int lch = pch ^ (line & 7);     // logical chunk
            const int row = ((lch >> 2) << 7) + line;
            const int kc = (lch & 3) << 3;        // k offset in elements
            gload_lds16(A + (rowA0 + row) * K + k0 + kc, (char*)&As[b][0] + c * 16);
            gload_lds16(Bt + (rowB0 + row) * K + k0 + kc, (char*)&Bs[b][0] + c * 16);
        }
    };
    auto compute = [&](int b) {
        const short* Ab = &As[b][0];
        const short* Bb = &Bs[b][0];
        short8 af[8], bf[4];
#pragma unroll
        for (int m = 0; m < 8; ++m) {
            const int line = m * 16 + l16;        // A row = wr*128 + line
            const int pch = ((wr << 2) + lhi) ^ (line & 7);
            af[m] = *(const short8*)(Ab + line * 64 + pch * 8);
        }
#pragma unroll
        for (int n = 0; n < 4; ++n) {
            const int row = wc * 64 + n * 16 + l16;
            const int line = row & 127;
            const int pch = (((row >> 7) << 2) + lhi) ^ (line & 7);
            bf[n] = *(const short8*)(Bb + line * 64 + pch * 8);
        }
#pragma unroll
        for (int m = 0; m < 8; ++m)
#pragma unroll
            for (int n = 0; n < 4; ++n)
                acc[m][n] = __builtin_amdgcn_mfma_f32_16x16x32_bf16(
                    af[m], bf[n], acc[m][n], 0, 0, 0);
    };

    const int ktiles = K >> 5;                    // 32 for K=1024
    stage(0, 0);
    stage(1, 1);
    stage(2, 2);
    for (int t = 0; t < ktiles; ++t) {
        const int rem = ktiles - 1 - t;
        if (rem >= 2)      asm volatile("s_waitcnt vmcnt(8)" ::: "memory");
        else if (rem == 1) asm volatile("s_waitcnt vmcnt(4)" ::: "memory");
        else               asm volatile("s_waitcnt vmcnt(0)" ::: "memory");
        __builtin_amdgcn_s_barrier();
        __builtin_amdgcn_sched_barrier(0);
        if (t + 3 < ktiles) stage(t + 3, (t + 3) & 3);   // after barrier: slot free
        compute(t & 3);
    }

#pragma unroll
    for (int m = 0; m < 8; ++m) {
        const long r0 = rowA0 + wr * 128 + m * 16 + lhi * 4;
#pragma unroll
        for (int n = 0; n < 4; ++n) {
            const long cc = rowB0 + wc * 64 + n * 16 + l16;
            const float bv = bias[cc];
#pragma unroll
            for (int j = 0; j < 4; ++j) {
                const long idx = (r0 + j) * N + cc;
                float v = acc[m][n][j] + bv;
                if (EPI == 2) {
                    float g = 0.5f * v *
                        (1.0f + tanhf(0.7978845608028654f * (v + 0.044715f * v * v * v)));
                    outB[idx] = f2bf(g);
                } else {
                    outF[idx] = v;
                }
            }
        }
    }
}

// ---------------------------------------------------------------------------
// gemm_rb64: 128x64 tile, BK=64, 4 waves (2x2), for the N=1024 GEMMs (Wo,
// MLP2).  3-slot LDS ring (72 KB), prefetch depth 2, counted vmcnt(6) per
// K-step (6 loads/thread/stage: 4 A + 2 B).  Chunk-XOR swizzle: LDS dest
// linear, inverse-swizzled GLOBAL source, swizzled ds_read (rule 21) ->
// <=2-way bank aliasing (free).  outF = acc + bias + res (f32).
// ---------------------------------------------------------------------------
__launch_bounds__(256, 2)
__global__ void gemm_rb64(const short* __restrict__ A, const short* __restrict__ Bt,
                          const float* __restrict__ bias, const float* __restrict__ res,
                          float* __restrict__ outF, int N, int K) {
    __shared__ __align__(16) short As[3][128 * 64];
    __shared__ __align__(16) short Bs[3][64 * 64];
    const int tid = threadIdx.x;
    const int lane = tid & 63, w = tid >> 6;
    const int wr = w >> 1, wc = w & 1;
    const int l16 = lane & 15, lhi = lane >> 4;

    const int nwg = gridDim.x * gridDim.y;
    int id = xcd_swizzle(blockIdx.y * gridDim.x + blockIdx.x, nwg);
    const int bx = id % gridDim.x, by = id / gridDim.x;
    const long rowA0 = (long)by * 128;
    const long rowB0 = (long)bx * 64;

    const f32x4 fz = {0.f, 0.f, 0.f, 0.f};
    f32x4 acc[4][2];
#pragma unroll
    for (int m = 0; m < 4; ++m)
#pragma unroll
        for (int n = 0; n < 2; ++n) acc[m][n] = fz;

    auto stage = [&](int kt, int b) {
        const int k0 = kt << 6;
#pragma unroll
        for (int it = 0; it < 4; ++it) {          // A: 1024 chunks
            const int c = it * 256 + tid;
            const int row = c >> 3;
            const int col = ((c & 7) ^ (row & 7)) << 3;
            gload_lds16(A + (rowA0 + row) * K + k0 + col, (char*)&As[b][0] + c * 16);
        }
#pragma unroll
        for (int it = 0; it < 2; ++it) {          // B: 512 chunks
            const int c = it * 256 + tid;
            const int row = c >> 3;
            const int col = ((c & 7) ^ (row & 7)) << 3;
            gload_lds16(Bt + (rowB0 + row) * K + k0 + col, (char*)&Bs[b][0] + c * 16);
        }
    };
    auto compute = [&](int b) {
        const short* Ab = &As[b][0];
        const short* Bb = &Bs[b][0];
#pragma unroll
        for (int kk = 0; kk < 2; ++kk) {
            short8 af[4], bf[2];
#pragma unroll
            for (int m = 0; m < 4; ++m) {
                const int row = wr * 64 + m * 16 + l16;
                const int pch = (kk * 4 + lhi) ^ (row & 7);
                af[m] = *(const short8*)(Ab + row * 64 + pch * 8);
            }
#pragma unroll
            for (int n = 0; n < 2; ++n) {
                const int row = wc * 32 + n * 16 + l16;
                const int pch = (kk * 4 + lhi) ^ (row & 7);
                bf[n] = *(const short8*)(Bb + row * 64 + pch * 8);
            }
#pragma unroll
            for (int m = 0; m < 4; ++m)
#pragma unroll
                for (int n = 0; n < 2; ++n)
                    acc[m][n] = __builtin_amdgcn_mfma_f32_16x16x32_bf16(
                        af[m], bf[n], acc[m][n], 0, 0, 0);
        }
    };

    const int ktiles = K >> 6;                    // 16 (Wo) or 64 (MLP2)
    stage(0, 0);
    stage(1, 1);
    for (int t = 0; t < ktiles; ++t) {
        if (t + 1 < ktiles) asm volatile("s_waitcnt vmcnt(6)" ::: "memory");
        else                asm volatile("s_waitcnt vmcnt(0)" ::: "memory");
        __builtin_amdgcn_s_barrier();
        __builtin_amdgcn_sched_barrier(0);
        if (t + 2 < ktiles) stage(t + 2, (t + 2) % 3);   // slot consumed at t-1
        compute(t % 3);
    }

#pragma unroll
    for (int m = 0; m < 4; ++m) {
        const long r0 = rowA0 + wr * 64 + m * 16 + lhi * 4;
#pragma unroll
        for (int n = 0; n < 2; ++n) {
            const long cc = rowB0 + wc * 32 + n * 16 + l16;
            const float bv = bias[cc];
#pragma unroll
            for (int j = 0; j < 4; ++j) {
                const long idx = (r0 + j) * N + cc;
                outF[idx] = acc[m][n][j] + bv + res[idx];
            }
        }
    }
}

// ---------------------------------------------------------------------------
// QKV post: per-(row,head) rmsnorm(d=64) + RoPE; write Q,K bf16 [BH][T][64].
// One wave per (row,head); 1/sqrt(HD)=1/8 folded into Q.  (V handled by
// transpose_v.)
// ---------------------------------------------------------------------------
__global__ void qkv_post(const float* __restrict__ qkv, const float* __restrict__ cosT,
                         const float* __restrict__ sinT, unsigned short* __restrict__ Qo,
                         unsigned short* __restrict__ Ko) {
    const int lane = threadIdx.x & 63;
    const int g = blockIdx.x * 4 + (threadIdx.x >> 6);
    const int row = g >> 4, h = g & 15;
    const int b = row >> 11, t = row & 2047;
    const float* base = qkv + (long)row * 3072 + h * 64;
    float q = base[lane];
    float k = base[1024 + lane];
    float sq = q * q, sk = k * k;
#pragma unroll
    for (int m = 32; m >= 1; m >>= 1) {
        sq += __shfl_xor(sq, m);
        sk += __shfl_xor(sk, m);
    }
    q *= rsqrtf(sq * (1.0f / 64.0f) + 1e-6f);
    k *= rsqrtf(sk * (1.0f / 64.0f) + 1e-6f);
    const int j = lane & 31;
    const float c = cosT[t * 32 + j], s = sinT[t * 32 + j];
    const float q2 = __shfl_xor(q, 32), k2 = __shfl_xor(k, 32);
    const float sgn = (lane < 32) ? 1.0f : -1.0f;   // y1 = x1*c + x2*s ; y2 = -x1*s + x2*c
    const float qr = q * c + sgn * q2 * s;
    const float kr = k * c + sgn * k2 * s;
    const long o = ((long)(b * 16 + h) * SEQ + t) * 64 + lane;
    Qo[o] = f2bf(qr * 0.125f);
    Ko[o] = f2bf(kr);
}

// ---------------------------------------------------------------------------
// V transpose: qkv f32 [M][3072] (V at col 2048+h*64+d) -> Vt bf16 [BH][64 d][T].
// Block per (bh, 64-row t-tile); LDS 64x65 f32 tile.
// ---------------------------------------------------------------------------
__global__ void transpose_v(const float* __restrict__ qkv,
                            unsigned short* __restrict__ Vt) {
    __shared__ float tile[64][65];
    const int tid = threadIdx.x;
    const int bh = blockIdx.x, tt = blockIdx.y;
    const int b = bh >> 4, h = bh & 15;
    const int tr = tid >> 2, c0 = (tid & 3) * 16;
    const float* src = qkv + ((long)(b * SEQ + tt * 64 + tr)) * 3072 + 2048 + h * 64 + c0;
#pragma unroll
    for (int i = 0; i < 4; ++i) {
        float4 v = ((const float4*)src)[i];
        tile[tr][c0 + i * 4 + 0] = v.x;
        tile[tr][c0 + i * 4 + 1] = v.y;
        tile[tr][c0 + i * 4 + 2] = v.z;
        tile[tr][c0 + i * 4 + 3] = v.w;
    }
    __syncthreads();
    const int d = tid >> 2, t0 = (tid & 3) * 16;
    unsigned short* dst = Vt + ((long)bh * 64 + d) * SEQ + tt * 64 + t0;
#pragma unroll
    for (int half = 0; half < 2; ++half) {
        u16x8 o;
#pragma unroll
        for (int e = 0; e < 8; ++e) o[e] = f2bf(tile[t0 + half * 8 + e][d]);
        *(u16x8*)(dst + half * 8) = o;
    }
}

// ---------------------------------------------------------------------------
// Causal flash attention. Block = 4 waves; Q-tile = 64 rows (16/wave); KV tile 64.
// SWAPPED QK^T: s = mfma(K, Q) so each 4-lane group owns a full q-row
// (q = lane&15, kv = frag index) -> in-lane softmax reduce + 2 shfl.
// P written [q][kv] with 4 x ds_write_b64, read back as PV A-frags (b128).
// K/V tiles double-buffered (stage(kt+1) before compute(kt)).
// Causal tiles paired: block i does qt=31-i then qt=i -> 33 steps/block flat.
// T13 defer-max: skip O-rescale when __all(pm <= m+8).
// ---------------------------------------------------------------------------
__launch_bounds__(256)
__global__ void attn_fwd(const short* __restrict__ Qg, const short* __restrict__ Kg,
                         const short* __restrict__ Vtg, unsigned short* __restrict__ Og) {
    __shared__ short Ks[2][64 * 64];          // [kv][d], chunk-XOR-swizzled
    __shared__ short Vs[2][64 * 64];          // [d][kv], chunk-XOR-swizzled
    __shared__ char Ps[4][2048];              // per-wave P [16 q][64 kv], swizzled
    const int tid = threadIdx.x, lane = tid & 63, w = tid >> 6;
    const int l16 = lane & 15, lhi = lane >> 4;
    const int id = xcd_swizzle(blockIdx.y * gridDim.x + blockIdx.x, 512);
    const int bh = id >> 4;
    const int ip = id & 15;
    const int bb = bh >> 4, hh = bh & 15;
    const long base_q = (long)bh * (SEQ * 64);
    char* Pw = &Ps[w][0];
    const int swz = (l16 & 7) << 4;
    const f32x4 fz = {0.f, 0.f, 0.f, 0.f};

#pragma unroll 1
    for (int rep = 0; rep < 2; ++rep) {
        const int qt = rep ? ip : 31 - ip;
        short8 aq0, aq1;
        {
            const short* Qp = Qg + base_q + (long)(qt * 64 + w * 16) * 64;
            aq0 = *(const short8*)(Qp + l16 * 64 + lhi * 8);
            aq1 = *(const short8*)(Qp + l16 * 64 + 32 + lhi * 8);
        }
        float mrow = -1e30f, lrow = 0.f;
        f32x4 oacc[4];
#pragma unroll
        for (int n = 0; n < 4; ++n) oacc[n] = fz;

        auto stage = [&](int kt, int b) {
            const short* Kp = Kg + base_q + (long)kt * 64 * 64;
            const short* Vp = Vtg + base_q + (long)kt * 64;
#pragma unroll
            for (int it = 0; it < 2; ++it) {
                const int c = it * 256 + tid;
                const int r = c >> 3;
                const int col = ((c & 7) ^ (r & 7)) << 3;
                gload_lds16(Kp + r * 64 + col, (char*)&Ks[b][0] + c * 16);
                gload_lds16(Vp + (long)r * SEQ + col, (char*)&Vs[b][0] + c * 16);
            }
        };

        stage(0, 0);
        __syncthreads();
        int cur = 0;
        for (int kt = 0; kt <= qt; ++kt) {
            if (kt < qt) stage(kt + 1, cur ^ 1);
            const short* KsC = &Ks[cur][0];
            const short* VsC = &Vs[cur][0];

            // S^T = K Q^T per wave: frag n covers kv = n*16..n*16+15 for the
            // wave's 16 q.  Lane holds s[n][j] = S[kv=n*16+lhi*4+j][q=l16].
            f32x4 s[4];
            __builtin_amdgcn_s_setprio(1);
#pragma unroll
            for (int n = 0; n < 4; ++n) {
                const int kr = n * 16 + l16;
                short8 bk0 = *(const short8*)(KsC + kr * 64 + ((lhi ^ (kr & 7)) << 3));
                short8 bk1 = *(const short8*)(KsC + kr * 64 + (((lhi + 4) ^ (kr & 7)) << 3));
                f32x4 z = fz;
                z = __builtin_amdgcn_mfma_f32_16x16x32_bf16(bk0, aq0, z, 0, 0, 0);
                s[n] = __builtin_amdgcn_mfma_f32_16x16x32_bf16(bk1, aq1, z, 0, 0, 0);
            }
            __builtin_amdgcn_s_setprio(0);
            if (kt == qt) {   // diagonal tile causal mask: kv_local > q_local
#pragma unroll
                for (int n = 0; n < 4; ++n)
#pragma unroll
                    for (int j = 0; j < 4; ++j)
                        if (n * 16 + lhi * 4 + j > w * 16 + l16) s[n][j] = -1e30f;
            }

            // online softmax: lane owns 16 of the 64 kv for q=l16; full-row
            // reduce = in-lane + shfl_xor(16,32).
            float pm = s[0][0];
#pragma unroll
            for (int n = 0; n < 4; ++n)
#pragma unroll
                for (int j = 0; j < 4; ++j) pm = fmaxf(pm, s[n][j]);
            pm = fmaxf(pm, __shfl_xor(pm, 16));
            pm = fmaxf(pm, __shfl_xor(pm, 32));
            if (!__all(pm <= mrow + 8.f)) {       // T13 defer-max
                const float newm = fmaxf(mrow, pm);
                const float sc = __expf(mrow - newm);
                mrow = newm;
                lrow *= sc;
#pragma unroll
                for (int j = 0; j < 4; ++j) {
                    const float scj = __shfl(sc, lhi * 4 + j);
#pragma unroll
                    for (int n = 0; n < 4; ++n) oacc[n][j] *= scj;
                }
            }
            float ps = 0.f;
#pragma unroll
            for (int n = 0; n < 4; ++n)
#pragma unroll
                for (int j = 0; j < 4; ++j) {
                    const float p = __expf(s[n][j] - mrow);
                    s[n][j] = p;
                    ps += p;
                }
            ps += __shfl_xor(ps, 16);
            ps += __shfl_xor(ps, 32);
            lrow += ps;

            // P[q=l16][kv=n*16+lhi*4 ..+3]: one packed b64 write per n-frag
#pragma unroll
            for (int n = 0; n < 4; ++n) {
                u16x4 pk;
                pk[0] = f2bf(s[n][0]);
                pk[1] = f2bf(s[n][1]);
                pk[2] = f2bf(s[n][2]);
                pk[3] = f2bf(s[n][3]);
                *(u16x4*)(Pw + ((l16 * 128 + n * 32 + lhi * 8) ^ swz)) = pk;
            }

            // O += P @ V : A-frag b128 from P[q][kv], B-frag from Vs
            __builtin_amdgcn_s_setprio(1);
#pragma unroll
            for (int ks = 0; ks < 2; ++ks) {
                short8 pa = *(const short8*)(Pw + ((l16 * 128 + ks * 64 + lhi * 16) ^ swz));
#pragma unroll
                for (int n = 0; n < 4; ++n) {
                    const int dr = n * 16 + l16;
                    short8 vb = *(const short8*)(VsC + dr * 64 + ((((ks << 2) + lhi) ^ (dr & 7)) << 3));
                    oacc[n] = __builtin_amdgcn_mfma_f32_16x16x32_bf16(pa, vb, oacc[n], 0, 0, 0);
                }
            }
            __builtin_amdgcn_s_setprio(0);
            __syncthreads();
            cur ^= 1;
        }

        // epilogue: O row q=lhi*4+j needs lrow held by lane q (l16=q)
#pragma unroll
        for (int j = 0; j < 4; ++j) {
            const float lr = __shfl(lrow, lhi * 4 + j);
            const int qrow = qt * 64 + w * 16 + lhi * 4 + j;
            const long orow = (long)bb * SEQ + qrow;
#pragma unroll
            for (int n = 0; n < 4; ++n)
                Og[orow * DMODEL + hh * 64 + n * 16 + l16] = f2bf(oacc[n][j] / lr);
        }
    }
}

// ---------------------------------------------------------------------------
extern "C" void kernel_launch(void* const* d_in, const int* in_sizes, int n_in,
                              void* d_out, int out_size, void* d_ws, size_t ws_size,
                              hipStream_t stream) {
    const float* x    = (const float*)d_in[0];
    // d_in[1] = block_mask (causal tril) — implicit in the attention kernel
    const float* Wqkv = (const float*)d_in[2];
    const float* bqkv = (const float*)d_in[3];
    const float* Wo   = (const float*)d_in[4];
    const float* bo   = (const float*)d_in[5];
    const float* W1   = (const float*)d_in[6];
    const float* b1   = (const float*)d_in[7];
    const float* W2   = (const float*)d_in[8];
    const float* b2   = (const float*)d_in[9];
    float* out = (float*)d_out;

    char* ws = (char*)d_ws;
    auto alloc = [&](size_t b) {
        char* p = ws;
        ws += (b + 255) & ~(size_t)255;
        return p;
    };
    short* WqkvT = (short*)alloc(3072ull * 1024 * 2);   // [3072][1024]
    short* WoT   = (short*)alloc(1024ull * 1024 * 2);   // [1024][1024]
    short* W1T   = (short*)alloc(4096ull * 1024 * 2);   // [4096][1024]
    short* W2T   = (short*)alloc(1024ull * 4096 * 2);   // [1024][4096]
    float* cosT  = (float*)alloc(2048ull * 32 * 4);
    float* sinT  = (float*)alloc(2048ull * 32 * 4);
    short* hbuf  = (short*)alloc((size_t)MROWS * DMODEL * 2);   // h1 / h2 (shared)
    short* Qb    = (short*)alloc(32ull * SEQ * 64 * 2);
    short* Kb    = (short*)alloc(32ull * SEQ * 64 * 2);
    short* Vtb   = (short*)alloc(32ull * 64 * SEQ * 2);         // V^T per head
    short* Ob    = (short*)alloc((size_t)MROWS * DMODEL * 2);
    float* x1    = (float*)alloc((size_t)MROWS * DMODEL * 4);
    char*  big   = alloc((size_t)MROWS * 3072 * 4);     // qkv f32, later act bf16
    float* qkv   = (float*)big;
    unsigned short* act = (unsigned short*)big;

    // 1. weights -> bf16 transposed
    cast_transpose<<<dim3(96, 32), 256, 0, stream>>>(Wqkv, (unsigned short*)WqkvT, 1024, 3072);
    cast_transpose<<<dim3(32, 32), 256, 0, stream>>>(Wo, (unsigned short*)WoT, 1024, 1024);
    cast_transpose<<<dim3(128, 32), 256, 0, stream>>>(W1, (unsigned short*)W1T, 1024, 4096);
    cast_transpose<<<dim3(32, 128), 256, 0, stream>>>(W2, (unsigned short*)W2T, 4096, 1024);
    // 2. RoPE tables
    rope_table<<<2048, 32, 0, stream>>>(cosT, sinT);
    // 3. h1 = rmsnorm(x)
    rmsnorm_cast<<<MROWS, 256, 0, stream>>>(x, (unsigned short*)hbuf);
    // 4. qkv = h1 @ Wqkv + bqkv   (256^2 ring-buffer GEMM, 192 blocks)
    gemm256<0><<<dim3(12, 16), 512, 0, stream>>>(hbuf, WqkvT, bqkv, qkv, nullptr, 3072, 1024);
    // 5a. per-head rmsnorm + rope -> Q,K bf16
    qkv_post<<<16384, 256, 0, stream>>>(qkv, cosT, sinT,
                                        (unsigned short*)Qb, (unsigned short*)Kb);
    // 5b. V -> bf16 transposed per head
    transpose_v<<<dim3(32, 32), 256, 0, stream>>>(qkv, (unsigned short*)Vtb);
    // 6. causal attention -> O  (512 balanced blocks: qt pairs)
    attn_fwd<<<dim3(16, 32), 256, 0, stream>>>(Qb, Kb, Vtb, (unsigned short*)Ob);
    // 7. x1 = O @ Wo + bo + x  (ring-buffer 128x64, 512 blocks)
    gemm_rb64<<<dim3(16, 32), 256, 0, stream>>>(Ob, WoT, bo, x, x1, 1024, 1024);
    // 8. h2 = rmsnorm(x1)
    rmsnorm_cast<<<MROWS, 256, 0, stream>>>(x1, (unsigned short*)hbuf);
    // 9. act = gelu(h2 @ W1 + b1)   (256^2 ring-buffer GEMM, 256 blocks)
    gemm256<2><<<dim3(16, 16), 512, 0, stream>>>(hbuf, W1T, b1, nullptr, act, 4096, 1024);
    // 10. out = act @ W2 + b2 + x1  (ring-buffer 128x64, 512 blocks)
    gemm_rb64<<<dim3(16, 32), 256, 0, stream>>>((const short*)act, W2T, b2, x1, out, 1024, 4096);
}